// Round 19
// baseline (68.659 us; speedup 1.0000x reference)
//
#include <hip/hip_runtime.h>
#include <hip/hip_bf16.h>

// FConv2d, round 20b (2nd resubmit; r17/r18 acquisition timeouts — no data):
// LDS-staged epilogue -> full-line single-visit stores. (20 fixed:
// __builtin_nontemporal_store needs clang ext_vector ptr, use floatx4.)
// Ledger: r16 WRITE 45 (poison evict), r18 WRITE 77 + FETCH 34~=8.4+2x16.8
// (half-dirty out lines evicted, re-fetched, re-written), r19 nt-only +0.7us.
// => out-line lifecycle is the residual: halves written ~us apart, lines
// make 2 round trips. Fix: accumulate accs in regs, barrier, write the
// block's full 32KB out tile into LDS (aliased over xs - dead after
// compute), barrier, stream out: each thread 4x floatx4 nt stores, each
// wave-instruction = 1KB contiguous = 8 FULL 128-B lines, each line
// written once, completely, atomically-in-time. No partial lines ever.
// Compute/staging/swizzle IDENTICAL to r17/r19 (verified, absmax 0.015625).
// Identity: out[b,d*16+n,r,s] = sum 0.5W[n,c2,2-u,2-v]*(xa+xb)[r+u,s+v];
// d=0/8: xa==xb -> acc doubled; mirror d'=16-d same values.

typedef __attribute__((ext_vector_type(8))) short short8;
typedef __attribute__((ext_vector_type(4))) float floatx4;

#define NT 512
#define LCH 168                 // padded channel-slot dim (160 used)
#define SROWS 34                // cols per staged row (32..33 zero apron)
#define XSROW (SROWS * LCH)

template<int D, bool DUP>
__device__ __forceinline__ floatx4 compute_d_acc(const char* basep, const short8 af[9]) {
    floatx4 a0 = {0.f,0.f,0.f,0.f}, a1 = {0.f,0.f,0.f,0.f};
    floatx4 b0 = {0.f,0.f,0.f,0.f}, b1 = {0.f,0.f,0.f,0.f};
#pragma unroll
    for (int u = 0; u < 3; ++u)
#pragma unroll
        for (int v = 0; v < 3; ++v) {
            const int t = u * 3 + v;
            const short8 ba = *(const short8*)(basep +
                ((u * SROWS + v) * LCH + 8 * (8 + D)) * 2);
            if (t & 1) a1 = __builtin_amdgcn_mfma_f32_16x16x32_bf16(af[t], ba, a1, 0, 0, 0);
            else       a0 = __builtin_amdgcn_mfma_f32_16x16x32_bf16(af[t], ba, a0, 0, 0, 0);
            if (!DUP) {
                const short8 bb = *(const short8*)(basep +
                    ((u * SROWS + v) * LCH + 8 * (8 - D)) * 2);
                if (t & 1) b1 = __builtin_amdgcn_mfma_f32_16x16x32_bf16(af[t], bb, b1, 0, 0, 0);
                else       b0 = __builtin_amdgcn_mfma_f32_16x16x32_bf16(af[t], bb, b0, 0, 0, 0);
            }
        }
    floatx4 acc = a0 + a1;
    if (DUP) acc = acc + acc;          // xa==xb: 2*(0.5W*xa) = W*xa, bit-identical
    else     acc = acc + (b0 + b1);
    return acc;
}

__global__ __launch_bounds__(NT, 4)
void fconv_mfma(const float* __restrict__ x,
                const float* __restrict__ wgt,
                float* __restrict__ out) {
    __shared__ __align__(16) short xs[3 * XSROW];   // 34,272 B; epilogue aliases 32KB
    __shared__ __align__(16) short wf[9 * 640];     // 11,520 B

    const int bid = blockIdx.x;    // 0..511
    const int b   = (bid & 7) + (((bid >> 3) & 1) << 3);   // batch->XCD swizzle
    const int r   = bid >> 4;                              // 0..31
    const int tid  = threadIdx.x;
    const int lane = tid & 63;
    const int wv   = tid >> 6;

    // ---- weights -> LDS: wf[(8-k)*640 + n*40 + oct*8 + (7-j)] = 0.5*W[n][8oct+j][k]
    {
        const int nn = tid >> 5;        // 0..15
        const int c2 = tid & 31;
        const float* wb = wgt + (size_t)(nn * 32 + c2) * 9;
        const int pos = nn * 40 + (c2 & 24) + (7 - (c2 & 7));
#pragma unroll
        for (int k = 0; k < 9; ++k) {
            __hip_bfloat16 h = __float2bfloat16(0.5f * wb[k]);
            wf[(8 - k) * 640 + pos] = __builtin_bit_cast(short, h);
        }
    }

    // ---- stage raw x rows r..r+2: 1920 granule tasks (lrow, col, oL) ----
    const float* xb_base = x + ((size_t)b << 17);
#pragma unroll
    for (int it = 0; it < 4; ++it) {
        const int idx = it * NT + tid;            // 0..2047
        if (idx < 1920) {
            const int col  = idx & 31;
            const int rest = idx >> 5;            // 0..59
            const int oL   = rest / 3;            // 0..19
            const int lrow = rest - oL * 3;       // 0..2
            const int grow = r + lrow;
            short8 g;
            if (grow < 32) {
                float v[8];
#pragma unroll
                for (int j = 0; j < 8; ++j) {
                    const int m = (oL * 8 + j - 95) & 127;   // channel (L-95) mod 128
                    v[j] = xb_base[((m << 5) + grow) * 32 + col];
                }
                union { __hip_bfloat162 h2[4]; short8 s8; } u;
#pragma unroll
                for (int p = 0; p < 4; ++p)
                    u.h2[p] = __float22bfloat162_rn(make_float2(v[2 * p], v[2 * p + 1]));
                g = u.s8;
            } else {
                g = short8{0, 0, 0, 0, 0, 0, 0, 0};
            }
            *(short8*)&xs[(lrow * SROWS + col) * LCH + oL * 8] = g;
        }
    }
    // s-apron (col 32,33) zeros: 3 lrow * 2 col * 20 oL = 120 granules
    if (tid < 120) {
        const int oL   = tid % 20;
        const int rem  = tid / 20;       // 0..5
        const int lrow = rem >> 1;
        const int col  = 32 + (rem & 1);
        short8 z = {0, 0, 0, 0, 0, 0, 0, 0};
        *(short8*)&xs[(lrow * SROWS + col) * LCH + oL * 8] = z;
    }

    __syncthreads();

    // ---- A fragments: 9 ds_read_b128 ----
    const int n = lane & 15;      // filter row / D col lane
    const int q = lane >> 4;      // k-octet
    short8 af[9];
#pragma unroll
    for (int t = 0; t < 9; ++t)
        af[t] = *(const short8*)&wf[t * 640 + n * 40 + q * 8];

    // ---- compute into registers: wave = one d-group, both col-halves ----
    const char* bp0 = (const char*)xs + ((0  + n) * LCH + 8 * (3 - q)) * 2;
    const char* bp1 = (const char*)xs + ((16 + n) * LCH + 8 * (3 - q)) * 2;
    floatx4 r00 = {0.f,0.f,0.f,0.f}, r01 = {0.f,0.f,0.f,0.f};   // d-slot 0, i=0/1
    floatx4 r10 = {0.f,0.f,0.f,0.f}, r11 = {0.f,0.f,0.f,0.f};   // d-slot 1 (wv0 only)
    int dA = -1, dB = -1;
    switch (wv) {
    case 0: r00 = compute_d_acc<0, true >(bp0, af);
            r01 = compute_d_acc<0, true >(bp1, af);
            r10 = compute_d_acc<8, true >(bp0, af);
            r11 = compute_d_acc<8, true >(bp1, af); dA = 0; dB = 8; break;
    case 1: r00 = compute_d_acc<4, false>(bp0, af);
            r01 = compute_d_acc<4, false>(bp1, af); dA = 4; break;
    case 2: r00 = compute_d_acc<2, false>(bp0, af);
            r01 = compute_d_acc<2, false>(bp1, af); dA = 2; break;
    case 3: r00 = compute_d_acc<6, false>(bp0, af);
            r01 = compute_d_acc<6, false>(bp1, af); dA = 6; break;
    case 4: r00 = compute_d_acc<1, false>(bp0, af);
            r01 = compute_d_acc<1, false>(bp1, af); dA = 1; break;
    case 5: r00 = compute_d_acc<5, false>(bp0, af);
            r01 = compute_d_acc<5, false>(bp1, af); dA = 5; break;
    case 6: r00 = compute_d_acc<3, false>(bp0, af);
            r01 = compute_d_acc<3, false>(bp1, af); dA = 3; break;
    default: r00 = compute_d_acc<7, false>(bp0, af);
             r01 = compute_d_acc<7, false>(bp1, af); dA = 7; break;
    }

    __syncthreads();   // all xs reads done; safe to alias epilogue tile over xs

    // ---- write out tile to LDS: ot[ch][s], ch = d*16+q*4+reg, s = s0+n ----
    float* ot = (float*)xs;        // 8192 floats = 32KB <= 34,272B
    {
        const int chb = q * 4;
#pragma unroll
        for (int reg = 0; reg < 4; ++reg) {
            const float v0 = r00[reg], v1 = r01[reg];
            ot[(dA * 16 + chb + reg) * 32 + n]      = v0;
            ot[(dA * 16 + chb + reg) * 32 + 16 + n] = v1;
            if (dA >= 1 && dA <= 7) {    // mirror channel group 16-dA
                ot[((16 - dA) * 16 + chb + reg) * 32 + n]      = v0;
                ot[((16 - dA) * 16 + chb + reg) * 32 + 16 + n] = v1;
            }
        }
        if (dB >= 0) {                   // wv0 second d-group (d=8, no mirror)
#pragma unroll
            for (int reg = 0; reg < 4; ++reg) {
                ot[(dB * 16 + chb + reg) * 32 + n]      = r10[reg];
                ot[(dB * 16 + chb + reg) * 32 + 16 + n] = r11[reg];
            }
        }
    }

    __syncthreads();

    // ---- stream out: 4x (ds_read_b128 + nt floatx4 store); per wave-instr
    //      1KB contiguous tile span = 8 FULL 128-B lines, single visit ----
    float* ob = out + ((size_t)b << 18) + r * 32;   // b*256*1024 + r*32
#pragma unroll
    for (int k = 0; k < 4; ++k) {
        const int idx = k * 2048 + tid * 4;         // 0..8188, exact cover
        const floatx4 v = *(const floatx4*)&ot[idx];
        const int ch = idx >> 5;
        const int s  = idx & 31;
        __builtin_nontemporal_store(v, (floatx4*)(ob + ch * 1024 + s));
    }
}

extern "C" void kernel_launch(void* const* d_in, const int* in_sizes, int n_in,
                              void* d_out, int out_size, void* d_ws, size_t ws_size,
                              hipStream_t stream) {
    const float* x   = (const float*)d_in[0];   // (16,128,32,32) fp32
    const float* wgt = (const float*)d_in[1];   // (16,32,3,3)   fp32
    float* out = (float*)d_out;                 // (16,256,32,32) fp32
    (void)in_sizes; (void)n_in; (void)out_size; (void)d_ws; (void)ws_size;

    fconv_mfma<<<dim3(512), dim3(NT), 0, stream>>>(x, wgt, out);
}